// Round 10
// baseline (2859.355 us; speedup 1.0000x reference)
//
#include <hip/hip_runtime.h>
#include <stdint.h>

#define T_SEQ 256
#define NB    8
#define EMB   512
#define HID   1024
#define NOUT  32000
#define RING  16
#define SEN   0x40004000u
#define RBLK  16

typedef float    f32x4  __attribute__((ext_vector_type(4)));
typedef unsigned int u32x4 __attribute__((ext_vector_type(4)));
typedef __bf16   bf16x8 __attribute__((ext_vector_type(8)));

#define AS1 __attribute__((address_space(1)))
#define AS3 __attribute__((address_space(3)))

__device__ __forceinline__ uint32_t f2bf(float f) {
    uint32_t u = __builtin_bit_cast(uint32_t, f);
    u += 0x7FFFu + ((u >> 16) & 1u);   // RNE
    return (u >> 16);
}

__device__ __forceinline__ bf16x8 mk_hi(u32x4 a, u32x4 b) {
    u32x4 r;
    r.x = __builtin_amdgcn_perm(a.y, a.x, 0x07060302u);
    r.y = __builtin_amdgcn_perm(a.w, a.z, 0x07060302u);
    r.z = __builtin_amdgcn_perm(b.y, b.x, 0x07060302u);
    r.w = __builtin_amdgcn_perm(b.w, b.z, 0x07060302u);
    return __builtin_bit_cast(bf16x8, r);
}
__device__ __forceinline__ bf16x8 mk_lo(u32x4 a, u32x4 b) {
    u32x4 r;
    r.x = __builtin_amdgcn_perm(a.y, a.x, 0x05040100u);
    r.y = __builtin_amdgcn_perm(a.w, a.z, 0x05040100u);
    r.z = __builtin_amdgcn_perm(b.y, b.x, 0x05040100u);
    r.w = __builtin_amdgcn_perm(b.w, b.z, 0x05040100u);
    return __builtin_bit_cast(bf16x8, r);
}

// ---------------- sentinel fill of the packed-h ring (R6-proven) ----------------
__global__ void k_fill(unsigned int* __restrict__ p) {  // RING*8*1024 u32 = 512 KB
    int i = blockIdx.x * blockDim.x + threadIdx.x;      // 128 x 256 x 4
    unsigned int* a = p + (size_t)i * 4;
#pragma unroll
    for (int j = 0; j < 4; ++j)
        (void)__hip_atomic_exchange(a + j, SEN, __ATOMIC_RELAXED, __HIP_MEMORY_SCOPE_AGENT);
}

// ---------------- W_fc fp32 -> bf16 ----------------
__global__ void k_convert_wfc(const float* __restrict__ src, unsigned short* __restrict__ dst) {
    int i = blockIdx.x * blockDim.x + threadIdx.x;
    const f32x4* s4 = (const f32x4*)src;
    int n4 = NOUT * HID / 4;
    int stride = gridDim.x * blockDim.x;
    for (int idx = i; idx < n4; idx += stride) {
        f32x4 v = s4[idx];
        uint2 o;
        o.x = f2bf(v.x) | (f2bf(v.y) << 16);
        o.y = f2bf(v.z) | (f2bf(v.w) << 16);
        ((uint2*)dst)[idx] = o;
    }
}

// ---------------- embed gather + xproj = emb @ W_ih^T + b_ih (fp32) ----------------
__global__ __launch_bounds__(256) void k_xproj(
        const int* __restrict__ inputs, const float* __restrict__ embed,
        const float* __restrict__ W_ih, const float* __restrict__ b_ih,
        float* __restrict__ xproj) {
    __shared__ float As[64][33];
    __shared__ float Bs[64][33];
    __shared__ int   idx_s[64];
    const int tid = threadIdx.x;
    const int bm = blockIdx.y, bn = blockIdx.x;
    if (tid < 64) {
        int m = bm * 64 + tid;
        idx_s[tid] = inputs[(m & 7) * T_SEQ + (m >> 3)];
    }
    __syncthreads();
    const int ty = tid >> 4, tx = tid & 15;
    const int lr = tid >> 2, lc = (tid & 3) * 8;
    float acc[4][4] = {};
    for (int kk = 0; kk < EMB; kk += 32) {
        __syncthreads();
        const float* arow = embed + (size_t)idx_s[lr] * EMB + kk + lc;
        f32x4 a0 = *(const f32x4*)arow;
        f32x4 a1 = *(const f32x4*)(arow + 4);
        const float* brow = W_ih + (size_t)(bn * 64 + lr) * EMB + kk + lc;
        f32x4 b0 = *(const f32x4*)brow;
        f32x4 b1 = *(const f32x4*)(brow + 4);
#pragma unroll
        for (int u = 0; u < 4; ++u) {
            As[lr][lc + u] = a0[u]; As[lr][lc + 4 + u] = a1[u];
            Bs[lr][lc + u] = b0[u]; Bs[lr][lc + 4 + u] = b1[u];
        }
        __syncthreads();
#pragma unroll
        for (int k = 0; k < 32; ++k) {
            float av[4], bv[4];
#pragma unroll
            for (int i = 0; i < 4; ++i) av[i] = As[ty * 4 + i][k];
#pragma unroll
            for (int j = 0; j < 4; ++j) bv[j] = Bs[tx * 4 + j][k];
#pragma unroll
            for (int i = 0; i < 4; ++i)
#pragma unroll
                for (int j = 0; j < 4; ++j) acc[i][j] += av[i] * bv[j];
        }
    }
#pragma unroll
    for (int i = 0; i < 4; ++i) {
        int m = bm * 64 + ty * 4 + i;
#pragma unroll
        for (int j = 0; j < 4; ++j) {
            int n = bn * 64 + tx * 4 + j;
            xproj[(size_t)m * HID + n] = acc[i][j] + b_ih[n];
        }
    }
}

// ============== recurrence: 16 blocks x 4 WAVE-AUTONOMOUS workers ==============
// Protocol bit-identical to R6 (PASSED): sentinel ring hpk[16][8][1024], publish
// via device-scope atomic_exchange, polls via sc0 sc1 loads. Work distribution
// changed: each WAVE owns 16 cols with full K=1024 in registers (whi/wlo[32],
// 256 VGPR) -> poll -> 96 MFMA -> tanh -> publish, with NO __syncthreads and
// NO LDS join anywhere in the step loop.
#define CKQ(q) bad |= (uint32_t)((q.x == SEN) | (q.y == SEN) | (q.z == SEN) | (q.w == SEN))

#define DO_CHUNK(qa, qb, WH, WL, ACC) do {                                      \
    bf16x8 ah = mk_hi(qa, qb);                                                  \
    bf16x8 al = mk_lo(qa, qb);                                                  \
    ACC = __builtin_amdgcn_mfma_f32_16x16x32_bf16(ah, WH, ACC, 0, 0, 0);        \
    ACC = __builtin_amdgcn_mfma_f32_16x16x32_bf16(al, WH, ACC, 0, 0, 0);        \
    ACC = __builtin_amdgcn_mfma_f32_16x16x32_bf16(ah, WL, ACC, 0, 0, 0);        \
} while (0)

__global__ __launch_bounds__(256, 1) void k_rnn(
        const float* __restrict__ W_hh, const float* __restrict__ b_hh,
        const float* __restrict__ xproj,
        unsigned int* __restrict__ hpk /* [RING][8][1024] u32 */,
        unsigned short* __restrict__ hs /* [2048][1024] bf16 */) {
    const int tid = threadIdx.x;
    const int w   = tid >> 6;
    const int ln  = tid & 63;
    const int blk = blockIdx.x;
    const int col0 = blk * 64 + w * 16;      // this wave's 16 columns

    // W preload: whi/wlo[cc] covers k = cc*32 (+ lane sub-range), cols col0..col0+15
    const float* wrow = W_hh + (size_t)(col0 + (ln & 15)) * HID;
    bf16x8 whi[32], wlo[32];
#pragma unroll
    for (int cc = 0; cc < 32; ++cc) {
        int k0 = cc * 32 + (ln >> 4) * 8;
        f32x4 wa = *(const f32x4*)(wrow + k0);
        f32x4 wb = *(const f32x4*)(wrow + k0 + 4);
        float wv[8] = { wa.x, wa.y, wa.z, wa.w, wb.x, wb.y, wb.z, wb.w };
        uint32_t hu[8], lu[8];
#pragma unroll
        for (int j = 0; j < 8; ++j) {
            hu[j] = f2bf(wv[j]);
            float hif = __builtin_bit_cast(float, hu[j] << 16);
            lu[j] = f2bf(wv[j] - hif);
        }
        u32x4 ph = { hu[0] | (hu[1] << 16), hu[2] | (hu[3] << 16),
                     hu[4] | (hu[5] << 16), hu[6] | (hu[7] << 16) };
        u32x4 pl = { lu[0] | (lu[1] << 16), lu[2] | (lu[3] << 16),
                     lu[4] | (lu[5] << 16), lu[6] | (lu[7] << 16) };
        whi[cc] = __builtin_bit_cast(bf16x8, ph);
        wlo[cc] = __builtin_bit_cast(bf16x8, pl);
    }
    const float bhh = b_hh[col0 + (ln & 15)];

    for (int t = 0; t < T_SEQ; ++t) {
        // xproj prefetch (cached), issued before the poll
        float xp[4];
        {
            int colp = col0 + (ln & 15);
            int bb = (ln >> 4) * 4;
#pragma unroll
            for (int r = 0; r < 4; ++r) {
                int b = (bb + r) & 7;
                xp[r] = xproj[(size_t)(t * NB + b) * HID + colp];
            }
        }

        f32x4 acc0 = {0.f, 0.f, 0.f, 0.f}, acc1 = {0.f, 0.f, 0.f, 0.f};
        if (t > 0) {
#pragma unroll
            for (int g = 0; g < 8; ++g) {
                // group g: chunks 4g..4g+3 (k = g*128 .. g*128+127)
                const unsigned int* hp = hpk + (size_t)((t - 1) & (RING - 1)) * 8192
                                             + (ln & 7) * 1024 + g * 128 + (ln >> 4) * 8;
                u32x4 q0, q1, q2, q3, q4, q5, q6, q7;
                uint32_t bad;
                do {
                    asm volatile(
                        "global_load_dwordx4 %0, %8, off sc0 sc1\n\t"
                        "global_load_dwordx4 %1, %8, off offset:16 sc0 sc1\n\t"
                        "global_load_dwordx4 %2, %8, off offset:128 sc0 sc1\n\t"
                        "global_load_dwordx4 %3, %8, off offset:144 sc0 sc1\n\t"
                        "global_load_dwordx4 %4, %8, off offset:256 sc0 sc1\n\t"
                        "global_load_dwordx4 %5, %8, off offset:272 sc0 sc1\n\t"
                        "global_load_dwordx4 %6, %8, off offset:384 sc0 sc1\n\t"
                        "global_load_dwordx4 %7, %8, off offset:400 sc0 sc1\n\t"
                        "s_waitcnt vmcnt(0)"
                        : "=&v"(q0), "=&v"(q1), "=&v"(q2), "=&v"(q3),
                          "=&v"(q4), "=&v"(q5), "=&v"(q6), "=&v"(q7)
                        : "v"(hp)
                        : "memory");
                    bad = 0;
                    CKQ(q0); CKQ(q1); CKQ(q2); CKQ(q3);
                    CKQ(q4); CKQ(q5); CKQ(q6); CKQ(q7);
                } while (bad);
                DO_CHUNK(q0, q1, whi[g * 4 + 0], wlo[g * 4 + 0], acc0);
                DO_CHUNK(q2, q3, whi[g * 4 + 1], wlo[g * 4 + 1], acc1);
                DO_CHUNK(q4, q5, whi[g * 4 + 2], wlo[g * 4 + 2], acc0);
                DO_CHUNK(q6, q7, whi[g * 4 + 3], wlo[g * 4 + 3], acc1);
            }
        }
        f32x4 csum = acc0 + acc1;

        if (ln < 32) {   // C/D rows 0-7 = batch; lanes 0-31 cover 16 cols x 8 batch
            int colp = col0 + (ln & 15);
            int bb = (ln >> 4) * 4;
            unsigned int* slot_w = hpk + (size_t)(t & (RING - 1)) * 8192;
            unsigned int* slot_s = hpk + (size_t)((t + RING - 3) & (RING - 1)) * 8192;
#pragma unroll
            for (int r = 0; r < 4; ++r) {
                float x = xp[r] + csum[r] + bhh;
                float h = tanhf(x);
                uint32_t hi = f2bf(h);
                float hif = __builtin_bit_cast(float, hi << 16);
                uint32_t lo = f2bf(h - hif);
                uint32_t pk = (hi << 16) | lo;
                // publish + sentinel refill: device-scope atomic exchange (R6-proven)
                (void)__hip_atomic_exchange(slot_w + (bb + r) * 1024 + colp, pk,
                                            __ATOMIC_RELAXED, __HIP_MEMORY_SCOPE_AGENT);
                (void)__hip_atomic_exchange(slot_s + (bb + r) * 1024 + colp, SEN,
                                            __ATOMIC_RELAXED, __HIP_MEMORY_SCOPE_AGENT);
                // hs archive (plain cached; consumed by k_fc after kernel boundary)
                hs[(size_t)(t * NB + bb + r) * HID + colp] = (unsigned short)hi;
            }
        }
    }
}

// ---------------- fc: C[m][n] = hs[m][:] . W_fc[n][:] + b_fc[n], bf16 MFMA ----------------
// grid dim3(16,250): bm fast -> the 16 consumers of each B-tile dispatch adjacently
__global__ void k_fc(const unsigned short* __restrict__ A,   // [2048][1024] bf16
                     const unsigned short* __restrict__ Bw,  // [32000][1024] bf16
                     const float* __restrict__ bias,
                     float* __restrict__ out) {              // [8][256][32000] f32
    __shared__ __align__(16) unsigned short As[128 * 32];
    __shared__ __align__(16) unsigned short Bs[128 * 32];
    const int tid = threadIdx.x;
    const int w = tid >> 6, ln = tid & 63;
    const int bm = blockIdx.x, bn = blockIdx.y;
    const int wm = (w >> 1) * 64, wn = (w & 1) * 64;
    const int srow = tid >> 2;
    const int scol = (tid & 3) * 8;
    const unsigned short* Ag = A  + (size_t)(bm * 128 + srow) * 1024 + scol;
    const unsigned short* Bg = Bw + (size_t)(bn * 128 + srow) * 1024 + scol;
    unsigned short* ldsA0 = As + w * 512;
    unsigned short* ldsA1 = As + 2048 + w * 512;
    unsigned short* ldsB0 = Bs + w * 512;
    unsigned short* ldsB1 = Bs + 2048 + w * 512;

    f32x4 acc[4][4] = {};
    const int fr = ln & 15;
    const int kq = (ln >> 4) * 8;

    for (int kk = 0; kk < 1024; kk += 32) {
        __syncthreads();
        __builtin_amdgcn_global_load_lds((const AS1 void*)(Ag + kk),             (AS3 void*)ldsA0, 16, 0, 0);
        __builtin_amdgcn_global_load_lds((const AS1 void*)(Ag + 64 * 1024 + kk), (AS3 void*)ldsA1, 16, 0, 0);
        __builtin_amdgcn_global_load_lds((const AS1 void*)(Bg + kk),             (AS3 void*)ldsB0, 16, 0, 0);
        __builtin_amdgcn_global_load_lds((const AS1 void*)(Bg + 64 * 1024 + kk), (AS3 void*)ldsB1, 16, 0, 0);
        __syncthreads();
        bf16x8 af[4], bf[4];
#pragma unroll
        for (int i = 0; i < 4; ++i)
            af[i] = *(const bf16x8*)&As[(wm + i * 16 + fr) * 32 + kq];
#pragma unroll
        for (int j = 0; j < 4; ++j)
            bf[j] = *(const bf16x8*)&Bs[(wn + j * 16 + fr) * 32 + kq];
#pragma unroll
        for (int i = 0; i < 4; ++i)
#pragma unroll
            for (int j = 0; j < 4; ++j)
                acc[i][j] = __builtin_amdgcn_mfma_f32_16x16x32_bf16(af[i], bf[j], acc[i][j], 0, 0, 0);
    }

    const int fq = ln >> 4;
#pragma unroll
    for (int i = 0; i < 4; ++i) {
#pragma unroll
        for (int j = 0; j < 4; ++j) {
            int n = bn * 128 + wn + j * 16 + fr;
            float bv = bias[n];
#pragma unroll
            for (int r = 0; r < 4; ++r) {
                int m = bm * 128 + wm + i * 16 + fq * 4 + r;
                int t = m >> 3, b = m & 7;
                out[(size_t)b * T_SEQ * NOUT + (size_t)t * NOUT + n] = acc[i][j][r] + bv;
            }
        }
    }
}

extern "C" void kernel_launch(void* const* d_in, const int* in_sizes, int n_in,
                              void* d_out, int out_size, void* d_ws, size_t ws_size,
                              hipStream_t stream) {
    const int*   inputs = (const int*)d_in[0];
    const float* embed  = (const float*)d_in[1];
    const float* W_ih   = (const float*)d_in[2];
    const float* W_hh   = (const float*)d_in[3];
    const float* b_ih   = (const float*)d_in[4];
    const float* b_hh   = (const float*)d_in[5];
    const float* W_fc   = (const float*)d_in[6];
    const float* b_fc   = (const float*)d_in[7];
    float* out = (float*)d_out;

    char* ws = (char*)d_ws;
    unsigned int*   hpk   = (unsigned int*)(ws);                        // 512 KB
    float*          xproj = (float*)(ws + 524288);                      // 8 MB
    unsigned short* hs    = (unsigned short*)(ws + 524288 + 8388608);   // 4 MB
    unsigned short* wfcb  = (unsigned short*)(ws + 524288 + 8388608 + 4194304); // 64 MB

    k_fill<<<128, 256, 0, stream>>>(hpk);
    k_convert_wfc<<<2048, 256, 0, stream>>>(W_fc, wfcb);
    k_xproj<<<dim3(16, 32), 256, 0, stream>>>(inputs, embed, W_ih, b_ih, xproj);
    k_rnn<<<RBLK, 256, 0, stream>>>(W_hh, b_hh, xproj, hpk, hs);
    k_fc<<<dim3(16, 250), 256, 0, stream>>>(hs, wfcb, b_fc, out);
}

// Round 11
// 811.817 us; speedup vs baseline: 3.5222x; 3.5222x over previous
//
#include <hip/hip_runtime.h>
#include <stdint.h>

#define T_SEQ 256
#define NB    8
#define EMB   512
#define HID   1024
#define NOUT  32000
#define RING  16
#define SEN   0x40004000u

typedef float    f32x4  __attribute__((ext_vector_type(4)));
typedef unsigned int u32x4 __attribute__((ext_vector_type(4)));
typedef __bf16   bf16x8 __attribute__((ext_vector_type(8)));

#define AS1 __attribute__((address_space(1)))
#define AS3 __attribute__((address_space(3)))

__device__ __forceinline__ uint32_t f2bf(float f) {
    uint32_t u = __builtin_bit_cast(uint32_t, f);
    u += 0x7FFFu + ((u >> 16) & 1u);   // RNE
    return (u >> 16);
}

__device__ __forceinline__ bf16x8 mk_hi(u32x4 a, u32x4 b) {
    u32x4 r;
    r.x = __builtin_amdgcn_perm(a.y, a.x, 0x07060302u);
    r.y = __builtin_amdgcn_perm(a.w, a.z, 0x07060302u);
    r.z = __builtin_amdgcn_perm(b.y, b.x, 0x07060302u);
    r.w = __builtin_amdgcn_perm(b.w, b.z, 0x07060302u);
    return __builtin_bit_cast(bf16x8, r);
}
__device__ __forceinline__ bf16x8 mk_lo(u32x4 a, u32x4 b) {
    u32x4 r;
    r.x = __builtin_amdgcn_perm(a.y, a.x, 0x05040100u);
    r.y = __builtin_amdgcn_perm(a.w, a.z, 0x05040100u);
    r.z = __builtin_amdgcn_perm(b.y, b.x, 0x05040100u);
    r.w = __builtin_amdgcn_perm(b.w, b.z, 0x05040100u);
    return __builtin_bit_cast(bf16x8, r);
}

// ---------------- sentinel fill of the packed-h rings (R6-proven) ----------------
// hpk[8 chains][RING][1024] u32 = 512 KB total
__global__ void k_fill(unsigned int* __restrict__ p) {
    int i = blockIdx.x * blockDim.x + threadIdx.x;      // 128 x 256 x 4
    unsigned int* a = p + (size_t)i * 4;
#pragma unroll
    for (int j = 0; j < 4; ++j)
        (void)__hip_atomic_exchange(a + j, SEN, __ATOMIC_RELAXED, __HIP_MEMORY_SCOPE_AGENT);
}

// ---------------- W_fc fp32 -> bf16 ----------------
__global__ void k_convert_wfc(const float* __restrict__ src, unsigned short* __restrict__ dst) {
    int i = blockIdx.x * blockDim.x + threadIdx.x;
    const f32x4* s4 = (const f32x4*)src;
    int n4 = NOUT * HID / 4;
    int stride = gridDim.x * blockDim.x;
    for (int idx = i; idx < n4; idx += stride) {
        f32x4 v = s4[idx];
        uint2 o;
        o.x = f2bf(v.x) | (f2bf(v.y) << 16);
        o.y = f2bf(v.z) | (f2bf(v.w) << 16);
        ((uint2*)dst)[idx] = o;
    }
}

// ---------------- embed gather + xproj = emb @ W_ih^T + b_ih (fp32) ----------------
__global__ __launch_bounds__(256) void k_xproj(
        const int* __restrict__ inputs, const float* __restrict__ embed,
        const float* __restrict__ W_ih, const float* __restrict__ b_ih,
        float* __restrict__ xproj) {
    __shared__ float As[64][33];
    __shared__ float Bs[64][33];
    __shared__ int   idx_s[64];
    const int tid = threadIdx.x;
    const int bm = blockIdx.y, bn = blockIdx.x;
    if (tid < 64) {
        int m = bm * 64 + tid;
        idx_s[tid] = inputs[(m & 7) * T_SEQ + (m >> 3)];
    }
    __syncthreads();
    const int ty = tid >> 4, tx = tid & 15;
    const int lr = tid >> 2, lc = (tid & 3) * 8;
    float acc[4][4] = {};
    for (int kk = 0; kk < EMB; kk += 32) {
        __syncthreads();
        const float* arow = embed + (size_t)idx_s[lr] * EMB + kk + lc;
        f32x4 a0 = *(const f32x4*)arow;
        f32x4 a1 = *(const f32x4*)(arow + 4);
        const float* brow = W_ih + (size_t)(bn * 64 + lr) * EMB + kk + lc;
        f32x4 b0 = *(const f32x4*)brow;
        f32x4 b1 = *(const f32x4*)(brow + 4);
#pragma unroll
        for (int u = 0; u < 4; ++u) {
            As[lr][lc + u] = a0[u]; As[lr][lc + 4 + u] = a1[u];
            Bs[lr][lc + u] = b0[u]; Bs[lr][lc + 4 + u] = b1[u];
        }
        __syncthreads();
#pragma unroll
        for (int k = 0; k < 32; ++k) {
            float av[4], bv[4];
#pragma unroll
            for (int i = 0; i < 4; ++i) av[i] = As[ty * 4 + i][k];
#pragma unroll
            for (int j = 0; j < 4; ++j) bv[j] = Bs[tx * 4 + j][k];
#pragma unroll
            for (int i = 0; i < 4; ++i)
#pragma unroll
                for (int j = 0; j < 4; ++j) acc[i][j] += av[i] * bv[j];
        }
    }
#pragma unroll
    for (int i = 0; i < 4; ++i) {
        int m = bm * 64 + ty * 4 + i;
#pragma unroll
        for (int j = 0; j < 4; ++j) {
            int n = bn * 64 + tx * 4 + j;
            xproj[(size_t)m * HID + n] = acc[i][j] + b_ih[n];
        }
    }
}

// ========== recurrence: 8 independent batch-chains x 32 blocks x 32 cols ==========
// Protocol bit-identical to R6 (PASSED): sentinel ring, atomic-exchange publish,
// sc0 sc1 polls, RING=16, refill slot t+13. New partition: chain c owns batch
// row c only -> h per chain = 1024 packed u32 (4 KB). Each wave polls ONE
// dwordx4/lane (its 1 KB quarter), stages to LDS, MFMAs its K-half from LDS
// broadcast reads with W frags in regs (whi/wlo[16] = 128 VGPR, no spill).
#define DO_CHUNK(qa, qb, WH, WL, ACC) do {                                      \
    bf16x8 ah = mk_hi(qa, qb);                                                  \
    bf16x8 al = mk_lo(qa, qb);                                                  \
    ACC = __builtin_amdgcn_mfma_f32_16x16x32_bf16(ah, WH, ACC, 0, 0, 0);        \
    ACC = __builtin_amdgcn_mfma_f32_16x16x32_bf16(al, WH, ACC, 0, 0, 0);        \
    ACC = __builtin_amdgcn_mfma_f32_16x16x32_bf16(ah, WL, ACC, 0, 0, 0);        \
} while (0)

__global__ __launch_bounds__(256, 1) void k_rnn(
        const float* __restrict__ W_hh, const float* __restrict__ b_hh,
        const float* __restrict__ xproj,
        unsigned int* __restrict__ hpk /* [8][RING][1024] u32 */,
        unsigned short* __restrict__ hs /* [2048][1024] bf16 */) {
    __shared__ __align__(16) unsigned int hlds[1024];   // 4 KB: this chain's h_{t-1}
    __shared__ float part[2][4][16];                     // 512 B partial join
    const int tid = threadIdx.x;
    const int w   = tid >> 6;
    const int ln  = tid & 63;
    const int blk = blockIdx.x;
    const int chain  = blk >> 5;          // batch row 0..7
    const int member = blk & 31;          // 0..31
    const int cg = w & 1;                 // col group (16 cols each)
    const int kh = w >> 1;                // K half (512 wide)
    const int col0 = member * 32 + cg * 16;
    unsigned int* ring = hpk + (size_t)chain * (RING * 1024);

    // W fragments: whi/wlo[cc] covers k = kh*512 + cc*32, cols col0..col0+15
    const float* wrow = W_hh + (size_t)(col0 + (ln & 15)) * HID;
    bf16x8 whi[16], wlo[16];
#pragma unroll
    for (int cc = 0; cc < 16; ++cc) {
        int k0 = kh * 512 + cc * 32 + (ln >> 4) * 8;
        f32x4 wa = *(const f32x4*)(wrow + k0);
        f32x4 wb = *(const f32x4*)(wrow + k0 + 4);
        float wv[8] = { wa.x, wa.y, wa.z, wa.w, wb.x, wb.y, wb.z, wb.w };
        uint32_t hu[8], lu[8];
#pragma unroll
        for (int j = 0; j < 8; ++j) {
            hu[j] = f2bf(wv[j]);
            float hif = __builtin_bit_cast(float, hu[j] << 16);
            lu[j] = f2bf(wv[j] - hif);
        }
        u32x4 ph = { hu[0] | (hu[1] << 16), hu[2] | (hu[3] << 16),
                     hu[4] | (hu[5] << 16), hu[6] | (hu[7] << 16) };
        u32x4 pl = { lu[0] | (lu[1] << 16), lu[2] | (lu[3] << 16),
                     lu[4] | (lu[5] << 16), lu[6] | (lu[7] << 16) };
        whi[cc] = __builtin_bit_cast(bf16x8, ph);
        wlo[cc] = __builtin_bit_cast(bf16x8, pl);
    }
    const float bhh = (ln < 16) ? b_hh[col0 + ln] : 0.f;

    for (int t = 0; t < T_SEQ; ++t) {
        // xproj prefetch for epilogue (waves 0,1; lanes 0-15): 1 value
        float xp = 0.f;
        if (kh == 0 && ln < 16)
            xp = xproj[(size_t)(t * NB + chain) * HID + col0 + ln];

        // poll own 1KB quarter of chain's h_{t-1}: ONE dwordx4 per lane
        if (t > 0) {
            const unsigned int* hp = ring + (size_t)((t - 1) & (RING - 1)) * 1024
                                          + w * 256 + ln * 4;
            u32x4 q;
            do {
                asm volatile("global_load_dwordx4 %0, %1, off sc0 sc1\n\t"
                             "s_waitcnt vmcnt(0)"
                             : "=&v"(q) : "v"(hp) : "memory");
            } while (q.x == SEN || q.y == SEN || q.z == SEN || q.w == SEN);
            *(u32x4*)&hlds[w * 256 + ln * 4] = q;
        }
        __syncthreads();   // BARRIER 1: full h_{t-1} staged in LDS

        f32x4 acc0 = {0.f, 0.f, 0.f, 0.f}, acc1 = {0.f, 0.f, 0.f, 0.f};
        if (t > 0) {
            const int lsub = (ln >> 4) * 8;   // 0,8,16,24
#pragma unroll
            for (int cc = 0; cc < 16; ++cc) {
                int ab = kh * 512 + cc * 32 + lsub;
                u32x4 qa = *(const u32x4*)&hlds[ab];
                u32x4 qb = *(const u32x4*)&hlds[ab + 4];
                if (cc & 1) { DO_CHUNK(qa, qb, whi[cc], wlo[cc], acc1); }
                else        { DO_CHUNK(qa, qb, whi[cc], wlo[cc], acc0); }
            }
        }
        // partial for D row 0 (batch=chain) lives in lanes 0-15, reg .x
        if (ln < 16) part[t & 1][w][ln] = acc0.x + acc1.x;
        __syncthreads();   // BARRIER 2: partials ready; hlds safe to rewrite next step

        if (kh == 0 && ln < 16) {   // waves 0,1 finish their col groups in parallel
            float sum = part[t & 1][w][ln] + part[t & 1][w + 2][ln];
            int colp = col0 + ln;
            float x = xp + sum + bhh;
            float h = tanhf(x);
            uint32_t hi = f2bf(h);
            float hif = __builtin_bit_cast(float, hi << 16);
            uint32_t lo = f2bf(h - hif);
            uint32_t pk = (hi << 16) | lo;
            // publish + sentinel refill (device-scope atomics, R6-proven)
            (void)__hip_atomic_exchange(ring + (size_t)(t & (RING - 1)) * 1024 + colp,
                                        pk, __ATOMIC_RELAXED, __HIP_MEMORY_SCOPE_AGENT);
            (void)__hip_atomic_exchange(ring + (size_t)((t + RING - 3) & (RING - 1)) * 1024 + colp,
                                        SEN, __ATOMIC_RELAXED, __HIP_MEMORY_SCOPE_AGENT);
            // hs archive (plain cached; consumed by k_fc after kernel boundary)
            hs[(size_t)(t * NB + chain) * HID + colp] = (unsigned short)hi;
        }
    }
}

// ---------------- fc: C[m][n] = hs[m][:] . W_fc[n][:] + b_fc[n], bf16 MFMA ----------------
// grid dim3(16,250): bm fast -> the 16 consumers of each B-tile dispatch adjacently
__global__ void k_fc(const unsigned short* __restrict__ A,   // [2048][1024] bf16
                     const unsigned short* __restrict__ Bw,  // [32000][1024] bf16
                     const float* __restrict__ bias,
                     float* __restrict__ out) {              // [8][256][32000] f32
    __shared__ __align__(16) unsigned short As[128 * 32];
    __shared__ __align__(16) unsigned short Bs[128 * 32];
    const int tid = threadIdx.x;
    const int w = tid >> 6, ln = tid & 63;
    const int bm = blockIdx.x, bn = blockIdx.y;
    const int wm = (w >> 1) * 64, wn = (w & 1) * 64;
    const int srow = tid >> 2;
    const int scol = (tid & 3) * 8;
    const unsigned short* Ag = A  + (size_t)(bm * 128 + srow) * 1024 + scol;
    const unsigned short* Bg = Bw + (size_t)(bn * 128 + srow) * 1024 + scol;
    unsigned short* ldsA0 = As + w * 512;
    unsigned short* ldsA1 = As + 2048 + w * 512;
    unsigned short* ldsB0 = Bs + w * 512;
    unsigned short* ldsB1 = Bs + 2048 + w * 512;

    f32x4 acc[4][4] = {};
    const int fr = ln & 15;
    const int kq = (ln >> 4) * 8;

    for (int kk = 0; kk < 1024; kk += 32) {
        __syncthreads();
        __builtin_amdgcn_global_load_lds((const AS1 void*)(Ag + kk),             (AS3 void*)ldsA0, 16, 0, 0);
        __builtin_amdgcn_global_load_lds((const AS1 void*)(Ag + 64 * 1024 + kk), (AS3 void*)ldsA1, 16, 0, 0);
        __builtin_amdgcn_global_load_lds((const AS1 void*)(Bg + kk),             (AS3 void*)ldsB0, 16, 0, 0);
        __builtin_amdgcn_global_load_lds((const AS1 void*)(Bg + 64 * 1024 + kk), (AS3 void*)ldsB1, 16, 0, 0);
        __syncthreads();
        bf16x8 af[4], bf[4];
#pragma unroll
        for (int i = 0; i < 4; ++i)
            af[i] = *(const bf16x8*)&As[(wm + i * 16 + fr) * 32 + kq];
#pragma unroll
        for (int j = 0; j < 4; ++j)
            bf[j] = *(const bf16x8*)&Bs[(wn + j * 16 + fr) * 32 + kq];
#pragma unroll
        for (int i = 0; i < 4; ++i)
#pragma unroll
            for (int j = 0; j < 4; ++j)
                acc[i][j] = __builtin_amdgcn_mfma_f32_16x16x32_bf16(af[i], bf[j], acc[i][j], 0, 0, 0);
    }

    const int fq = ln >> 4;
#pragma unroll
    for (int i = 0; i < 4; ++i) {
#pragma unroll
        for (int j = 0; j < 4; ++j) {
            int n = bn * 128 + wn + j * 16 + fr;
            float bv = bias[n];
#pragma unroll
            for (int r = 0; r < 4; ++r) {
                int m = bm * 128 + wm + i * 16 + fq * 4 + r;
                int t = m >> 3, b = m & 7;
                out[(size_t)b * T_SEQ * NOUT + (size_t)t * NOUT + n] = acc[i][j][r] + bv;
            }
        }
    }
}

extern "C" void kernel_launch(void* const* d_in, const int* in_sizes, int n_in,
                              void* d_out, int out_size, void* d_ws, size_t ws_size,
                              hipStream_t stream) {
    const int*   inputs = (const int*)d_in[0];
    const float* embed  = (const float*)d_in[1];
    const float* W_ih   = (const float*)d_in[2];
    const float* W_hh   = (const float*)d_in[3];
    const float* b_ih   = (const float*)d_in[4];
    const float* b_hh   = (const float*)d_in[5];
    const float* W_fc   = (const float*)d_in[6];
    const float* b_fc   = (const float*)d_in[7];
    float* out = (float*)d_out;

    char* ws = (char*)d_ws;
    unsigned int*   hpk   = (unsigned int*)(ws);                        // 8*16*1024*4 = 512 KB
    float*          xproj = (float*)(ws + 524288);                      // 8 MB
    unsigned short* hs    = (unsigned short*)(ws + 524288 + 8388608);   // 4 MB
    unsigned short* wfcb  = (unsigned short*)(ws + 524288 + 8388608 + 4194304); // 64 MB

    k_fill<<<128, 256, 0, stream>>>(hpk);
    k_convert_wfc<<<2048, 256, 0, stream>>>(W_fc, wfcb);
    k_xproj<<<dim3(16, 32), 256, 0, stream>>>(inputs, embed, W_ih, b_ih, xproj);
    k_rnn<<<256, 256, 0, stream>>>(W_hh, b_hh, xproj, hpk, hs);
    k_fc<<<dim3(16, 250), 256, 0, stream>>>(hs, wfcb, b_fc, out);
}